// Round 1
// baseline (414.814 us; speedup 1.0000x reference)
//
#include <hip/hip_runtime.h>

// CIF (continuous integrate-and-fire) — MI355X
//
// Outputs (flat in d_out):
//   [0 .. T*H)            frame_sel = frames[0][idx]  (idx = fire steps of batch 0, padded with 0)
//   [T*H .. T*H+B)        integ_new [B]
//   [T*H+B .. T*H+B+B*H)  frame_new [B,H]
//
// Phase 1 (sequential, bit-exact vs reference op order): per-batch scalar scan over T.
//   Produces g[b][t] = fire ? rem : alpha  (forward weight of h_t),
//   cur0[t] (batch-0 spend weight), fire list of batch 0, row metadata, t_last per batch.
// Phase 2 (parallel): each output row is a short weighted segment-sum over hidden.

#define FIRE_THRESH 1.0f

__global__ __launch_bounds__(64) void cif_scan_kernel(
    const float* __restrict__ alphas,     // [B,T]
    const float* __restrict__ integrate0, // [B]
    float* __restrict__ g,                // ws [B*T]
    float* __restrict__ cur0,             // ws [T]
    int*   __restrict__ fire_t,           // ws [T]
    int*   __restrict__ rowStart,         // ws [T]
    int*   __restrict__ rowEnd,           // ws [T]
    int*   __restrict__ rowInit,          // ws [T]
    int*   __restrict__ tlast,            // ws [B]
    float* __restrict__ integ_out,        // d_out + T*H
    int B, int T)
{
    __shared__ int s_nf;
    const int b = threadIdx.x;
    if (b == 0) s_nf = 0;
    __syncthreads();

    if (b < B) {
        float integ = integrate0[b];
        int   last  = -1;
        int   nf    = 0;
        const float* ap = alphas + (size_t)b * T;
        float*       gp = g      + (size_t)b * T;
        for (int t0 = 0; t0 < T; t0 += 4) {
            float4 a4 = *reinterpret_cast<const float4*>(ap + t0);
            float av[4] = {a4.x, a4.y, a4.z, a4.w};
            float gv[4];
#pragma unroll
            for (int k = 0; k < 4; ++k) {
                const int t = t0 + k;
                const float alpha = av[k];
                const float dist  = 1.0f - integ;           // dist_completion
                integ = integ + alpha;                       // same op order as reference
                const bool fire = (integ >= FIRE_THRESH);
                const float cur = fire ? dist : alpha;
                const float rem = alpha - cur;
                gv[k] = fire ? rem : alpha;
                if (b == 0) {
                    cur0[t] = cur;
                    if (fire) fire_t[nf++] = t;
                }
                if (fire) { integ -= 1.0f; last = t; }       // exact (Sterbenz) subtraction
            }
            *reinterpret_cast<float4*>(gp + t0) =
                make_float4(gv[0], gv[1], gv[2], gv[3]);
        }
        integ_out[b] = integ;
        tlast[b]     = last;
        if (b == 0) s_nf = nf;
    }
    __syncthreads();

    const int nfires = s_nf;
    for (int r = threadIdx.x; r < T; r += 64) {
        if (r < nfires) {
            rowStart[r] = (r == 0) ? 0 : fire_t[r - 1];
            rowEnd[r]   = fire_t[r];
            rowInit[r]  = (r == 0) ? 1 : 0;
        } else {
            // padding row: frames[0][0] = frame_init[0] + cur0[0]*h[0,0]
            rowStart[r] = 0;
            rowEnd[r]   = 0;
            rowInit[r]  = 1;
        }
    }
}

__global__ __launch_bounds__(128) void cif_out_kernel(
    const float* __restrict__ hidden,   // [B,T,H]
    const float* __restrict__ frame0,   // [B,H] initial frame
    const float* __restrict__ g,        // [B*T]
    const float* __restrict__ cur0,     // [T]
    const int*   __restrict__ rowStart, // [T]
    const int*   __restrict__ rowEnd,   // [T]
    const int*   __restrict__ rowInit,  // [T]
    const int*   __restrict__ tlast,    // [B]
    float* __restrict__ out_sel,        // [T,H]
    float* __restrict__ frame_out,      // [B,H]
    int B, int T, int H)
{
    const int blk = blockIdx.x;

    if (blk < T) {
        // ---- frame_sel row r (batch 0) ----
        const int r     = blk;
        const int start = rowStart[r];
        const int end   = rowEnd[r];
        const int initf = rowInit[r];
        const float wend = cur0[end];
        for (int h0 = threadIdx.x * 4; h0 < H; h0 += 128 * 4) {
            float4 acc;
            if (initf) acc = *reinterpret_cast<const float4*>(frame0 + h0);
            else       acc = make_float4(0.f, 0.f, 0.f, 0.f);
            for (int s = start; s < end; ++s) {
                const float  w  = g[s]; // batch 0
                const float4 hv = *reinterpret_cast<const float4*>(hidden + (size_t)s * H + h0);
                acc.x += w * hv.x; acc.y += w * hv.y;
                acc.z += w * hv.z; acc.w += w * hv.w;
            }
            {
                const float4 hv = *reinterpret_cast<const float4*>(hidden + (size_t)end * H + h0);
                acc.x += wend * hv.x; acc.y += wend * hv.y;
                acc.z += wend * hv.z; acc.w += wend * hv.w;
            }
            *reinterpret_cast<float4*>(out_sel + (size_t)r * H + h0) = acc;
        }
    } else {
        // ---- frame_new for batch b ----
        const int b  = blk - T;
        const int tl = tlast[b];
        const int start = (tl < 0) ? 0 : tl;
        const float* gb = g      + (size_t)b * T;
        const float* hb = hidden + (size_t)b * T * H;
        for (int h0 = threadIdx.x * 4; h0 < H; h0 += 128 * 4) {
            float4 acc;
            if (tl < 0) acc = *reinterpret_cast<const float4*>(frame0 + (size_t)b * H + h0);
            else        acc = make_float4(0.f, 0.f, 0.f, 0.f);
            for (int s = start; s < T; ++s) {
                const float  w  = gb[s];
                const float4 hv = *reinterpret_cast<const float4*>(hb + (size_t)s * H + h0);
                acc.x += w * hv.x; acc.y += w * hv.y;
                acc.z += w * hv.z; acc.w += w * hv.w;
            }
            *reinterpret_cast<float4*>(frame_out + (size_t)b * H + h0) = acc;
        }
    }
}

extern "C" void kernel_launch(void* const* d_in, const int* in_sizes, int n_in,
                              void* d_out, int out_size, void* d_ws, size_t ws_size,
                              hipStream_t stream) {
    const float* hidden    = (const float*)d_in[0]; // [B,T,H]
    const float* alphas    = (const float*)d_in[1]; // [B,T]
    const float* integrate = (const float*)d_in[2]; // [B]
    const float* frame     = (const float*)d_in[3]; // [B,H]

    const int B = in_sizes[2];
    const int T = in_sizes[1] / B;
    const int H = in_sizes[3] / B;

    float* out       = (float*)d_out;
    float* out_sel   = out;                       // T*H
    float* integ_out = out + (size_t)T * H;       // B
    float* frame_out = integ_out + B;             // B*H

    char* ws = (char*)d_ws;
    float* g        = (float*)ws; ws += sizeof(float) * (size_t)B * T;
    float* cur0     = (float*)ws; ws += sizeof(float) * T;
    int*   fire_t   = (int*)ws;   ws += sizeof(int) * T;
    int*   rowStart = (int*)ws;   ws += sizeof(int) * T;
    int*   rowEnd   = (int*)ws;   ws += sizeof(int) * T;
    int*   rowInit  = (int*)ws;   ws += sizeof(int) * T;
    int*   tlast    = (int*)ws;   ws += sizeof(int) * B;

    cif_scan_kernel<<<1, 64, 0, stream>>>(
        alphas, integrate, g, cur0, fire_t, rowStart, rowEnd, rowInit, tlast,
        integ_out, B, T);

    cif_out_kernel<<<T + B, 128, 0, stream>>>(
        hidden, frame, g, cur0, rowStart, rowEnd, rowInit, tlast,
        out_sel, frame_out, B, T, H);
}

// Round 2
// 239.314 us; speedup vs baseline: 1.7333x; 1.7333x over previous
//
#include <hip/hip_runtime.h>

// CIF (continuous integrate-and-fire) — MI355X
//
// d_out layout: [0..T*H) frame_sel ; [T*H..T*H+B) integ_new ; then [B*H) frame_new
//
// K1: transpose alphas [B,T] -> aT4 [T/4][B] (float4 granules) for coalesced scan loads.
// K2: sequential scan, 1 block x 64 lanes (lane = batch). Register-pipelined 64-step
//     chunks (prefetch next 16 float4s while computing current). Bit-exact fire
//     pattern: s = integ+alpha ; fire = s>=1 ; integ' = fire ? s-1.0 : s.
//     g[t] = fire ? s-1.0 : alpha  (== reference's rem up to 1 ulp; frames have
//     7.9e-2 tolerance, fire pattern unaffected). Fire bits packed per-64-step mask.
//     Post-pass (all 64 threads): batch-0 fire list via popcount + wave prefix scan,
//     then per-output-row metadata (segment [start,end], flags).
// K3: parallel segment sums: row r of frame_sel = optional frame0 + sum g0[s]*h[0,s]
//     over [start,end) + wend*h[0,end];  frame_new[b] = sum over [tlast,T).

#define THRESH 1.0f
#define MAX_T 2048

__global__ __launch_bounds__(256) void cif_transpose_kernel(
    const float4* __restrict__ a4, float4* __restrict__ aT4, int B, int T4)
{
    int tid = blockIdx.x * blockDim.x + threadIdx.x;
    if (tid >= B * T4) return;
    int b = tid / T4, c = tid - b * T4;
    aT4[(size_t)c * B + b] = a4[tid];   // coalesced read, 16B-scattered write (tiny data)
}

__global__ __launch_bounds__(64) void cif_scan_kernel(
    const float4* __restrict__ aT4,            // [T/4][B]
    const float*  __restrict__ integ0,         // [B]
    float* __restrict__ gT,                    // [T][B]
    unsigned long long* __restrict__ fireMask, // [T/64][B]
    int* __restrict__ rowStart, int* __restrict__ rowEnd, int* __restrict__ rowFlags, // [T]
    int* __restrict__ tlast,                   // [B]
    float* __restrict__ integ_out,             // d_out + T*H
    int B, int T)
{
    const int lane = threadIdx.x;
    const int nchunk = T >> 6;                 // 64 steps per chunk
    __shared__ int s_fire[MAX_T];
    __shared__ unsigned long long s_mask[64];  // batch-0 per-chunk fire masks
    __shared__ int s_nf, s_f0;

    const bool act = lane < B;
    float integ = act ? integ0[lane] : 0.0f;
    int   lastc = -1;
    unsigned long long lastm = 0;

    float4 bufA[16], bufB[16];

#define LOADCH(buf, c) do { if (act) { \
    _Pragma("unroll") for (int j = 0; j < 16; ++j) \
        buf[j] = aT4[(size_t)((c) * 16 + j) * B + lane]; } } while (0)

#define DOCH(buf, c) do { if (act) { \
    unsigned lo = 0, hi = 0; \
    _Pragma("unroll") for (int j = 0; j < 16; ++j) { \
        const float av[4] = {buf[j].x, buf[j].y, buf[j].z, buf[j].w}; \
        _Pragma("unroll") for (int k = 0; k < 4; ++k) { \
            const int idx = j * 4 + k; \
            const float alpha = av[k]; \
            const float s   = integ + alpha;      /* exact ref op */ \
            const bool fire = (s >= THRESH);      /* exact ref op */ \
            const float sm1 = s - 1.0f;           /* exact ref op */ \
            integ = fire ? sm1 : s; \
            const float gv = fire ? sm1 : alpha;  /* == rem up to 1 ulp */ \
            if (idx < 32) lo |= fire ? (1u << idx) : 0u; \
            else          hi |= fire ? (1u << (idx - 32)) : 0u; \
            gT[(size_t)((c) * 64 + idx) * B + lane] = gv; \
        } } \
    const unsigned long long m = ((unsigned long long)hi << 32) | lo; \
    fireMask[(size_t)(c) * B + lane] = m; \
    if (lane == 0) s_mask[(c)] = m; \
    lastc = m ? (c) : lastc; \
    lastm = m ? m : lastm; \
    } } while (0)

    LOADCH(bufA, 0);
    for (int c = 0; c < nchunk; c += 2) {
        if (c + 1 < nchunk) LOADCH(bufB, c + 1);
        DOCH(bufA, c);
        if (c + 2 < nchunk) LOADCH(bufA, c + 2);
        if (c + 1 < nchunk) DOCH(bufB, c + 1);
    }
#undef LOADCH
#undef DOCH

    if (act) {
        integ_out[lane] = integ;
        tlast[lane] = (lastc >= 0) ? (lastc * 64 + 63 - __clzll(lastm)) : -1;
    }
    __syncthreads();

    // ---- batch-0 fire list: lane j owns chunk j ----
    unsigned long long m0 = (lane < nchunk) ? s_mask[lane] : 0ull;
    int pc = __popcll(m0);
    int x = pc;
#pragma unroll
    for (int d = 1; d < 64; d <<= 1) {
        int y = __shfl_up(x, d);
        if (lane >= d) x += y;
    }
    const int excl = x - pc;
    if (lane == 63) s_nf = x;
    if (lane == 0)  s_f0 = (int)(m0 & 1ull);
    {
        unsigned long long m = m0; int r = excl;
        while (m) {
            int p = __ffsll((unsigned long long)m) - 1;
            s_fire[r++] = lane * 64 + p;
            m &= m - 1;
        }
    }
    __syncthreads();

    const int nf = s_nf, f0 = s_f0;
    for (int r = lane; r < T; r += 64) {
        int st, en, fl;
        if (r < nf) {
            en = s_fire[r];
            st = (r == 0) ? 0 : s_fire[r - 1];
            fl = ((r == 0) ? 1 : 0) | 2;           // bit0: add frame0, bit1: end is a fire
        } else {                                    // padding row -> frames[0][0]
            st = 0; en = 0; fl = 1 | (f0 ? 2 : 0);
        }
        rowStart[r] = st; rowEnd[r] = en; rowFlags[r] = fl;
    }
}

__global__ __launch_bounds__(128) void cif_out_kernel(
    const float* __restrict__ hidden,   // [B,T,H]
    const float* __restrict__ frame0,   // [B,H]
    const float* __restrict__ gT,       // [T][B]
    const float* __restrict__ alphas,   // [B,T] (batch-0 row used for wend)
    const int* __restrict__ rowStart, const int* __restrict__ rowEnd,
    const int* __restrict__ rowFlags, const int* __restrict__ tlast,
    float* __restrict__ out_sel,        // [T,H]
    float* __restrict__ frame_out,      // [B,H]
    int B, int T, int H)
{
    const int blk = blockIdx.x;

    if (blk < T) {
        const int r = blk;
        const int start = rowStart[r], end = rowEnd[r], fl = rowFlags[r];
        const float a  = alphas[end];                  // batch 0
        const float ge = gT[(size_t)end * B];
        const float wend = (fl & 2) ? (a - ge) : a;    // cur at end (fire: alpha-rem; else alpha)
        for (int h0 = threadIdx.x * 4; h0 < H; h0 += 128 * 4) {
            float4 acc = (fl & 1) ? *reinterpret_cast<const float4*>(frame0 + h0)
                                  : make_float4(0.f, 0.f, 0.f, 0.f);
            for (int s = start; s < end; ++s) {
                const float  w  = gT[(size_t)s * B];
                const float4 hv = *reinterpret_cast<const float4*>(hidden + (size_t)s * H + h0);
                acc.x += w * hv.x; acc.y += w * hv.y;
                acc.z += w * hv.z; acc.w += w * hv.w;
            }
            const float4 hv = *reinterpret_cast<const float4*>(hidden + (size_t)end * H + h0);
            acc.x += wend * hv.x; acc.y += wend * hv.y;
            acc.z += wend * hv.z; acc.w += wend * hv.w;
            *reinterpret_cast<float4*>(out_sel + (size_t)r * H + h0) = acc;
        }
    } else {
        const int b  = blk - T;
        const int tl = tlast[b];
        const int start = (tl < 0) ? 0 : tl;
        const float* hb = hidden + (size_t)b * T * H;
        for (int h0 = threadIdx.x * 4; h0 < H; h0 += 128 * 4) {
            float4 acc = (tl < 0) ? *reinterpret_cast<const float4*>(frame0 + (size_t)b * H + h0)
                                  : make_float4(0.f, 0.f, 0.f, 0.f);
            for (int s = start; s < T; ++s) {
                const float  w  = gT[(size_t)s * B + b];
                const float4 hv = *reinterpret_cast<const float4*>(hb + (size_t)s * H + h0);
                acc.x += w * hv.x; acc.y += w * hv.y;
                acc.z += w * hv.z; acc.w += w * hv.w;
            }
            *reinterpret_cast<float4*>(frame_out + (size_t)b * H + h0) = acc;
        }
    }
}

extern "C" void kernel_launch(void* const* d_in, const int* in_sizes, int n_in,
                              void* d_out, int out_size, void* d_ws, size_t ws_size,
                              hipStream_t stream) {
    const float* hidden    = (const float*)d_in[0]; // [B,T,H]
    const float* alphas    = (const float*)d_in[1]; // [B,T]
    const float* integrate = (const float*)d_in[2]; // [B]
    const float* frame     = (const float*)d_in[3]; // [B,H]

    const int B = in_sizes[2];
    const int T = in_sizes[1] / B;
    const int H = in_sizes[3] / B;

    float* out       = (float*)d_out;
    float* out_sel   = out;                     // T*H
    float* integ_out = out + (size_t)T * H;     // B
    float* frame_out = integ_out + B;           // B*H

    char* ws = (char*)d_ws;
    float4* aT4 = (float4*)ws;                 ws += sizeof(float) * (size_t)B * T;
    float*  gT  = (float*)ws;                  ws += sizeof(float) * (size_t)B * T;
    unsigned long long* fireMask = (unsigned long long*)ws; ws += sizeof(unsigned long long) * (size_t)(T / 64) * B;
    int* rowStart = (int*)ws;                  ws += sizeof(int) * T;
    int* rowEnd   = (int*)ws;                  ws += sizeof(int) * T;
    int* rowFlags = (int*)ws;                  ws += sizeof(int) * T;
    int* tlast    = (int*)ws;                  ws += sizeof(int) * B;

    const int T4 = T / 4;
    cif_transpose_kernel<<<(B * T4 + 255) / 256, 256, 0, stream>>>(
        (const float4*)alphas, aT4, B, T4);

    cif_scan_kernel<<<1, 64, 0, stream>>>(
        aT4, integrate, gT, fireMask, rowStart, rowEnd, rowFlags, tlast,
        integ_out, B, T);

    cif_out_kernel<<<T + B, 128, 0, stream>>>(
        hidden, frame, gT, alphas, rowStart, rowEnd, rowFlags, tlast,
        out_sel, frame_out, B, T, H);
}

// Round 3
// 206.753 us; speedup vs baseline: 2.0063x; 1.1575x over previous
//
#include <hip/hip_runtime.h>

// CIF (continuous integrate-and-fire) — MI355X
//
// d_out layout: [0..T*H) frame_sel ; [T*H..T*H+B) integ_new ; then [B*H) frame_new
//
// K1 transpose: alphas [B,T] -> aT4 [T/4][B] (float4 granules), coalesced scan loads.
// K2 chain (serial, 1 wave): ONLY the irreducible recurrence
//       s = integ + alpha ; integ = fract(s)
//     which is bit-exact vs the reference's  fire = s>=1 ; integ' = fire ? s-1 : s
//     for s in [0,2) (alpha in [0,1), integ in [0,1)): Sterbenz => fract(s)=s-1 exact.
//     Emits per-64-step-chunk boundary integ values. ~2 VALU/step, no per-step VMEM.
// K3 replay (parallel, 1 block x 1024): thread (chunk c, batch b) replays its 64 steps
//     bit-exactly from the stored boundary integ, producing g[t][b] and fire masks;
//     then the block builds batch-0 fire list + per-row segment metadata + tlast.
// K4 out: parallel segment sums (unchanged from R1, which passed with absmax 0).

#define THRESH 1.0f
#define MAX_T 4096
#define MAX_CH 64

__device__ __forceinline__ float fract_exact(float x) {
    float r; asm("v_fract_f32 %0, %1" : "=v"(r) : "v"(x)); return r;
}

__global__ __launch_bounds__(256) void cif_transpose_kernel(
    const float4* __restrict__ a4, float4* __restrict__ aT4, int B, int T4)
{
    int tid = blockIdx.x * blockDim.x + threadIdx.x;
    if (tid >= B * T4) return;
    int b = tid / T4, c = tid - b * T4;
    aT4[(size_t)c * B + b] = a4[tid];
}

__global__ __launch_bounds__(64) void cif_chain_kernel(
    const float4* __restrict__ aT4,        // [T/4][B]
    const float*  __restrict__ integ0,     // [B]
    float* __restrict__ chunkInteg,        // [T/64][B] pre-chunk integ
    float* __restrict__ integ_out,         // d_out + T*H
    int B, int T)
{
    const int lane = threadIdx.x;
    const bool act = lane < B;
    const int nchunk = T >> 6;
    float integ = act ? integ0[lane] : 0.0f;
    float4 bufA[16], bufB[16];

#define LOADCH(buf, c) do { if (act) { \
    _Pragma("unroll") for (int j = 0; j < 16; ++j) \
        buf[j] = aT4[(size_t)((c) * 16 + j) * B + lane]; } } while (0)

#define DOCH(buf, c) do { if (act) { \
    chunkInteg[(size_t)(c) * B + lane] = integ; \
    _Pragma("unroll") for (int j = 0; j < 16; ++j) { \
        integ = fract_exact(integ + buf[j].x); \
        integ = fract_exact(integ + buf[j].y); \
        integ = fract_exact(integ + buf[j].z); \
        integ = fract_exact(integ + buf[j].w); \
    } } } while (0)

    LOADCH(bufA, 0);
    for (int c = 0; c < nchunk; c += 2) {
        if (c + 1 < nchunk) LOADCH(bufB, c + 1);
        DOCH(bufA, c);
        if (c + 2 < nchunk) LOADCH(bufA, c + 2);
        if (c + 1 < nchunk) DOCH(bufB, c + 1);
    }
#undef LOADCH
#undef DOCH

    if (act) integ_out[lane] = integ;
}

__global__ __launch_bounds__(1024) void cif_replay_kernel(
    const float4* __restrict__ aT4,        // [T/4][B]
    const float*  __restrict__ chunkInteg, // [T/64][B]
    float* __restrict__ gT,                // [T][B]
    int* __restrict__ rowStart, int* __restrict__ rowEnd, int* __restrict__ rowFlags, // [T]
    int* __restrict__ tlast,               // [B]
    int B, int T)
{
    const int nchunk = T >> 6;
    const int tid = threadIdx.x;
    __shared__ unsigned long long s_mask[2048];   // [c*B + b]
    __shared__ int s_fire[MAX_T];
    __shared__ int s_nf, s_f0;

    if (tid < nchunk * B) {
        const int c = tid / B, b = tid - c * B;   // b fastest -> coalesced
        float integ = chunkInteg[tid];
        unsigned long long m = 0;
        for (int j = 0; j < 16; ++j) {
            const float4 a4 = aT4[(size_t)(c * 16 + j) * B + b];
            const float av[4] = {a4.x, a4.y, a4.z, a4.w};
            float gv[4];
#pragma unroll
            for (int k = 0; k < 4; ++k) {
                const int idx = j * 4 + k;
                const float alpha = av[k];
                const float s   = integ + alpha;   // exact ref op order
                const bool fire = (s >= THRESH);
                const float sm1 = s - 1.0f;
                integ = fire ? sm1 : s;
                gv[k] = fire ? sm1 : alpha;
                m |= fire ? (1ull << idx) : 0ull;
            }
#pragma unroll
            for (int k = 0; k < 4; ++k)
                gT[(size_t)(c * 64 + j * 4 + k) * B + b] = gv[k];
        }
        s_mask[tid] = m;
    }
    __syncthreads();

    // tlast[b]: last fire over all chunks
    if (tid < B) {
        int tl = -1;
        for (int c = nchunk - 1; c >= 0; --c) {
            const unsigned long long mc = s_mask[c * B + tid];
            if (mc) { tl = c * 64 + 63 - __clzll(mc); break; }
        }
        tlast[tid] = tl;
    }

    // batch-0 fire list: first wave, lane c owns chunk c
    if (tid < 64) {
        unsigned long long m0 = (tid < nchunk) ? s_mask[tid * B] : 0ull;
        const int pc = __popcll(m0);
        int x = pc;
#pragma unroll
        for (int d = 1; d < 64; d <<= 1) {
            const int y = __shfl_up(x, d);
            if (tid >= d) x += y;
        }
        if (tid == 63) s_nf = x;
        if (tid == 0)  s_f0 = (int)(m0 & 1ull);
        int r = x - pc;
        while (m0) {
            const int p = __ffsll(m0) - 1;
            s_fire[r++] = tid * 64 + p;
            m0 &= m0 - 1;
        }
    }
    __syncthreads();

    const int nf = s_nf, f0 = s_f0;
    for (int r = tid; r < T; r += blockDim.x) {
        int st, en, fl;
        if (r < nf) {
            en = s_fire[r];
            st = (r == 0) ? 0 : s_fire[r - 1];
            fl = ((r == 0) ? 1 : 0) | 2;      // bit0: add frame0, bit1: end is a fire
        } else {                               // padding row -> frames[0][0]
            st = 0; en = 0; fl = 1 | (f0 ? 2 : 0);
        }
        rowStart[r] = st; rowEnd[r] = en; rowFlags[r] = fl;
    }
}

__global__ __launch_bounds__(128) void cif_out_kernel(
    const float* __restrict__ hidden,   // [B,T,H]
    const float* __restrict__ frame0,   // [B,H]
    const float* __restrict__ gT,       // [T][B]
    const float* __restrict__ alphas,   // [B,T] (batch-0 row used for wend)
    const int* __restrict__ rowStart, const int* __restrict__ rowEnd,
    const int* __restrict__ rowFlags, const int* __restrict__ tlast,
    float* __restrict__ out_sel,        // [T,H]
    float* __restrict__ frame_out,      // [B,H]
    int B, int T, int H)
{
    const int blk = blockIdx.x;

    if (blk < T) {
        const int r = blk;
        const int start = rowStart[r], end = rowEnd[r], fl = rowFlags[r];
        const float a  = alphas[end];                  // batch 0
        const float ge = gT[(size_t)end * B];
        const float wend = (fl & 2) ? (a - ge) : a;
        for (int h0 = threadIdx.x * 4; h0 < H; h0 += 128 * 4) {
            float4 acc = (fl & 1) ? *reinterpret_cast<const float4*>(frame0 + h0)
                                  : make_float4(0.f, 0.f, 0.f, 0.f);
            for (int s = start; s < end; ++s) {
                const float  w  = gT[(size_t)s * B];
                const float4 hv = *reinterpret_cast<const float4*>(hidden + (size_t)s * H + h0);
                acc.x += w * hv.x; acc.y += w * hv.y;
                acc.z += w * hv.z; acc.w += w * hv.w;
            }
            const float4 hv = *reinterpret_cast<const float4*>(hidden + (size_t)end * H + h0);
            acc.x += wend * hv.x; acc.y += wend * hv.y;
            acc.z += wend * hv.z; acc.w += wend * hv.w;
            *reinterpret_cast<float4*>(out_sel + (size_t)r * H + h0) = acc;
        }
    } else {
        const int b  = blk - T;
        const int tl = tlast[b];
        const int start = (tl < 0) ? 0 : tl;
        const float* hb = hidden + (size_t)b * T * H;
        for (int h0 = threadIdx.x * 4; h0 < H; h0 += 128 * 4) {
            float4 acc = (tl < 0) ? *reinterpret_cast<const float4*>(frame0 + (size_t)b * H + h0)
                                  : make_float4(0.f, 0.f, 0.f, 0.f);
            for (int s = start; s < T; ++s) {
                const float  w  = gT[(size_t)s * B + b];
                const float4 hv = *reinterpret_cast<const float4*>(hb + (size_t)s * H + h0);
                acc.x += w * hv.x; acc.y += w * hv.y;
                acc.z += w * hv.z; acc.w += w * hv.w;
            }
            *reinterpret_cast<float4*>(frame_out + (size_t)b * H + h0) = acc;
        }
    }
}

extern "C" void kernel_launch(void* const* d_in, const int* in_sizes, int n_in,
                              void* d_out, int out_size, void* d_ws, size_t ws_size,
                              hipStream_t stream) {
    const float* hidden    = (const float*)d_in[0]; // [B,T,H]
    const float* alphas    = (const float*)d_in[1]; // [B,T]
    const float* integrate = (const float*)d_in[2]; // [B]
    const float* frame     = (const float*)d_in[3]; // [B,H]

    const int B = in_sizes[2];
    const int T = in_sizes[1] / B;
    const int H = in_sizes[3] / B;

    float* out       = (float*)d_out;
    float* out_sel   = out;                     // T*H
    float* integ_out = out + (size_t)T * H;     // B
    float* frame_out = integ_out + B;           // B*H

    char* ws = (char*)d_ws;
    float4* aT4       = (float4*)ws;  ws += sizeof(float) * (size_t)B * T;
    float*  gT        = (float*)ws;   ws += sizeof(float) * (size_t)B * T;
    float*  chunkInteg= (float*)ws;   ws += sizeof(float) * (size_t)(T / 64) * B;
    int* rowStart = (int*)ws;         ws += sizeof(int) * T;
    int* rowEnd   = (int*)ws;         ws += sizeof(int) * T;
    int* rowFlags = (int*)ws;         ws += sizeof(int) * T;
    int* tlast    = (int*)ws;         ws += sizeof(int) * B;

    const int T4 = T / 4;
    cif_transpose_kernel<<<(B * T4 + 255) / 256, 256, 0, stream>>>(
        (const float4*)alphas, aT4, B, T4);

    cif_chain_kernel<<<1, 64, 0, stream>>>(
        aT4, integrate, chunkInteg, integ_out, B, T);

    cif_replay_kernel<<<1, 1024, 0, stream>>>(
        aT4, chunkInteg, gT, rowStart, rowEnd, rowFlags, tlast, B, T);

    cif_out_kernel<<<T + B, 128, 0, stream>>>(
        hidden, frame, gT, alphas, rowStart, rowEnd, rowFlags, tlast,
        out_sel, frame_out, B, T, H);
}